// Round 11
// baseline (103.330 us; speedup 1.0000x reference)
//
#include <hip/hip_runtime.h>

#define NN 2048
#define DD 64
#define BB 64
#define PP 16384
#define TT 262144
#define EPSF 1e-6f
#define SS ((size_t)NN * DD)  // floats between consecutive bins of v (bin-major)

// ---------------- ws layout (bytes) ----------------
// 0        : double acc
// 1024     : int cnt[2048]     (node-i histogram)
// 9216     : int cursor[2048]
// 17408    : int perm[PP]      (pair ids sorted by node i)
// 82944    : float bounds[65]
// 83456    : float widths[64]
// 83968    : float innerPad[64]
// 84480    : float4 table[PP*BB]  (n2_left, d0, qq, bsum) = 16.78 MB
// 16861696 : ushort vh[NN*BB*DD]  (bf16 node-major v)      = 16.78 MB
// total ~33.6 MB

typedef unsigned uv2 __attribute__((ext_vector_type(2)));

template <int CTRL, int RM = 0xF, bool BC = true>
__device__ __forceinline__ float dpp_add(float x) {
    int y = __builtin_amdgcn_update_dpp(0, __float_as_int(x), CTRL, RM, 0xF, BC);
    return x + __int_as_float(y);
}

template <int PAT>
__device__ __forceinline__ float swz_add(float x) {
    return x + __int_as_float(__builtin_amdgcn_ds_swizzle(__float_as_int(x), PAT));
}

// xor16 / xor32 adds on the VALU pipe (permlane swaps), LDS fallback if absent
__device__ __forceinline__ float xor16_add(float x) {
#if __has_builtin(__builtin_amdgcn_permlane16_swap)
    uv2 r = __builtin_amdgcn_permlane16_swap(__float_as_uint(x), __float_as_uint(x),
                                             false, false);
    return __uint_as_float(r.x) + __uint_as_float(r.y);
#else
    return swz_add<0x401F>(x);
#endif
}
__device__ __forceinline__ float xor32_add(float x) {
#if __has_builtin(__builtin_amdgcn_permlane32_swap)
    uv2 r = __builtin_amdgcn_permlane32_swap(__float_as_uint(x), __float_as_uint(x),
                                             false, false);
    return __uint_as_float(r.x) + __uint_as_float(r.y);
#else
    return x + __shfl_xor(x, 32, 64);
#endif
}

// full 64-lane sum, result on all lanes
__device__ __forceinline__ float reduce1(float a) {
    a = dpp_add<0xB1>(a);     // quad_perm xor1
    a = dpp_add<0x4E>(a);     // quad_perm xor2
    a = dpp_add<0x141>(a);    // row_half_mirror (completes sum of 8)
    a = swz_add<0x201F>(a);   // xor8
    a = xor16_add(a);
    a = xor32_add(a);
    return a;
}

// 64-lane inclusive prefix sum (canonical 6-DPP scan)
__device__ __forceinline__ float incl_scan(float x) {
    x = dpp_add<0x111>(x);             // row_shr:1
    x = dpp_add<0x112>(x);             // row_shr:2
    x = dpp_add<0x114>(x);             // row_shr:4
    x = dpp_add<0x118>(x);             // row_shr:8
    x = dpp_add<0x142, 0xA, false>(x); // row_bcast:15 -> rows 1,3
    x = dpp_add<0x143, 0xC, false>(x); // row_bcast:31 -> rows 2,3
    return x;
}

__device__ __forceinline__ unsigned short f2bf(float f) {  // RNE
    unsigned u = __float_as_uint(f);
    unsigned r = (u + 0x7FFFu + ((u >> 16) & 1u)) >> 16;
    return (unsigned short)r;
}
__device__ __forceinline__ float bf_lo(unsigned u) {  // low ushort -> float
    return __uint_as_float(u << 16);
}
__device__ __forceinline__ float bf_hi(unsigned u) {  // high ushort -> float
    return __uint_as_float(u & 0xFFFF0000u);
}

__global__ void k_bounds(const float* __restrict__ brw, float* __restrict__ bounds,
                         float* __restrict__ widths, float* __restrict__ innerPad,
                         int* __restrict__ cnt, double* __restrict__ acc) {
    if (blockIdx.x != 0) {
        // blocks 1..8: zero cnt[2048] and acc (absorbs the old memset dispatch)
        int t = (blockIdx.x - 1) * 64 + threadIdx.x;  // 0..511
#pragma unroll
        for (int k = 0; k < 4; k++) cnt[t * 4 + k] = 0;
        if (blockIdx.x == 1 && threadIdx.x == 0) acc[0] = 0.0;
        return;
    }
    int lane = threadIdx.x;  // 64 threads
    float w = brw[lane];
    float m = w;
#pragma unroll
    for (int s = 32; s >= 1; s >>= 1) m = fmaxf(m, __shfl_xor(m, s, 64));
    float e = expf(w - m);
    float tot = e;
#pragma unroll
    for (int s = 32; s >= 1; s >>= 1) tot += __shfl_xor(tot, s, 64);
    float sm = e / tot;
    float c = sm;  // inclusive prefix sum
#pragma unroll
    for (int off = 1; off < 64; off <<= 1) {
        float t = __shfl_up(c, off, 64);
        if (lane >= off) c += t;
    }
    float cexcl = __shfl_up(c, 1, 64);
    if (lane == 0) cexcl = 0.f;
    if (lane == 0) bounds[0] = 0.f;
    bounds[lane + 1] = c;
    widths[lane] = c - cexcl;
    innerPad[lane] = (lane == 63) ? 3.4e38f : c;  // inner = bounds[1..63]
}

// v[b][n][d] fp32 -> vh[n][b][d] bf16 (node-major: one node = contiguous 8KB)
__global__ __launch_bounds__(256) void k_convert(const float* __restrict__ v,
                                                 unsigned* __restrict__ vh32) {
    int wid = threadIdx.x >> 6, lane = threadIdx.x & 63;
    int n = blockIdx.x * 4 + wid;
    int sub = lane >> 5;            // 0..1: bin offset within iteration
    int dp = (lane & 31) * 2;       // dim pair start
    unsigned* __restrict__ dst = vh32 + ((size_t)n * BB * DD) / 2;
#pragma unroll
    for (int c = 0; c < 32; c++) {
        int b = c * 2 + sub;
        float2 f = *(const float2*)(v + (size_t)b * SS + (size_t)n * DD + dp);
        unsigned pk = (unsigned)f2bf(f.x) | ((unsigned)f2bf(f.y) << 16);
        dst[(b * DD + dp) / 2] = pk;
    }
}

__global__ void k_hist2(const int* __restrict__ pairs, int* __restrict__ cnt) {
    int t = blockIdx.x * 256 + threadIdx.x;  // t < PP; pairs[t] = node i
    atomicAdd(&cnt[pairs[t]], 1);
}

__global__ __launch_bounds__(1024) void k_scan2(const int* __restrict__ cnt,
                                                int* __restrict__ cursor) {
    __shared__ int waveTot[16];
    __shared__ int waveOff[16];
    int tid = threadIdx.x;  // 1024 threads, 2 entries each
    int a = cnt[tid * 2], b = cnt[tid * 2 + 1];
    int s = a + b;
    int lane = tid & 63, wid = tid >> 6;
    int incl = s;
#pragma unroll
    for (int off = 1; off < 64; off <<= 1) {
        int t2 = __shfl_up(incl, off, 64);
        if (lane >= off) incl += t2;
    }
    if (lane == 63) waveTot[wid] = incl;
    __syncthreads();
    if (tid == 0) {
        int r = 0;
        for (int w = 0; w < 16; w++) { waveOff[w] = r; r += waveTot[w]; }
    }
    __syncthreads();
    int run = waveOff[wid] + (incl - s);  // exclusive prefix for this thread
    cursor[tid * 2] = run;
    cursor[tid * 2 + 1] = run + a;
}

__global__ void k_scatter2(const int* __restrict__ pairs, int* __restrict__ cursor,
                           int* __restrict__ perm) {
    int t = blockIdx.x * 256 + threadIdx.x;
    int pos = atomicAdd(&cursor[pairs[t]], 1);
    perm[pos] = t;
}

__global__ __launch_bounds__(256) void k_pairs(
    const float* __restrict__ x0, const uint4* __restrict__ vh4,
    const float* __restrict__ beta, const int* __restrict__ pairs,
    const int* __restrict__ perm, const float* __restrict__ widths,
    float4* __restrict__ table, double* __restrict__ acc_out) {
    __shared__ float tile[4][8][68];  // per-wave bounce tile (blocked -> lane=dim)
    __shared__ double bacc[4];
    const int wid = threadIdx.x >> 6;
    const int lane = threadIdx.x & 63;
    const int bid = blockIdx.x;
    const int vb = ((bid & 7) << 9) | (bid >> 3);  // XCD-contiguous p-ranges (4096 blocks)
    const int p = perm[vb * 4 + wid];

    const int i = pairs[p];
    const int j = pairs[PP + p];
    const float bsum = beta[i] + beta[j];

    float dx0 = x0[i * DD + lane] - x0[j * DD + lane];
    float xt = dx0;
    float n2_0 = reduce1(dx0 * dx0);
    float rr0 = __builtin_amdgcn_sqrtf(n2_0);
    float numer0 = rr0 * __expf(bsum - rr0);

    // bf16 node-major: node block = 512 uint4 (8KB); chunk c = 64 uint4 (1KB).
    // lane l covers row (l>>3), dims 8*(l&7)..+7 (one ushort8 = uint4).
    const uint4* __restrict__ Vi = vh4 + (size_t)i * 512 + lane;
    const uint4* __restrict__ Vj = vh4 + (size_t)j * 512 + lane;

    float (*T)[68] = tile[wid];
    const int wrow = lane >> 3;          // LDS write row (0..7)
    const int wcol = (lane & 7) * 8;     // LDS write col start
    const int cls = lane & 7;            // class-select id
    const int grp = lane >> 3;           // chunk-gate id

    float d0r = 0.f, qqr = 0.f;  // lane b ends holding bin b's reduced d0, qq

    uint4 a0 = Vi[0];
    uint4 b0 = Vj[0];
    uint4 a1 = Vi[64];
    uint4 b1 = Vj[64];

#pragma unroll
    for (int c = 0; c < 8; c++) {
        uint4 a2, b2;
        if (c < 6) {  // 2-chunk-deep prefetch (1 dwordx4 per side)
            a2 = Vi[(c + 2) * 64];
            b2 = Vj[(c + 2) * 64];
        }
        // dv (fp32 from bf16) -> LDS, 2 x b128 per lane
        float4 lo, hi;
        lo.x = bf_lo(a0.x) - bf_lo(b0.x);  lo.y = bf_hi(a0.x) - bf_hi(b0.x);
        lo.z = bf_lo(a0.y) - bf_lo(b0.y);  lo.w = bf_hi(a0.y) - bf_hi(b0.y);
        hi.x = bf_lo(a0.z) - bf_lo(b0.z);  hi.y = bf_hi(a0.z) - bf_hi(b0.z);
        hi.z = bf_lo(a0.w) - bf_lo(b0.w);  hi.w = bf_hi(a0.w) - bf_hi(b0.w);
        *(float4*)&T[wrow][wcol] = lo;
        *(float4*)&T[wrow][wcol + 4] = hi;

        // lane=dim sweep over the 8 bins (same-wave DS ordering: reads see writes)
        float zd = 0.f, zq = 0.f;
#pragma unroll
        for (int b = 0; b < 8; b++) {
            float dv = T[b][lane];
            float d0p = xt * dv;
            float qqp = dv * dv;
            d0p = dpp_add<0xB1>(d0p);  qqp = dpp_add<0xB1>(qqp);   // xor1
            d0p = dpp_add<0x4E>(d0p);  qqp = dpp_add<0x4E>(qqp);   // xor2
            d0p = dpp_add<0x141>(d0p); qqp = dpp_add<0x141>(qqp);  // half-mirror
            if (cls == b) { zd = d0p; zq = qqp; }  // stash bin b's 8-partials
            xt = fmaf(dv, widths[c * 8 + b], xt);  // widths: scalar load
        }
        // cross-class finish for all 8 bins at once
        zd = swz_add<0x201F>(zd);  zq = swz_add<0x201F>(zq);  // xor8
        zd = xor16_add(zd);        zq = xor16_add(zq);
        zd = xor32_add(zd);        zq = xor32_add(zq);
        if (grp == c) { d0r = zd; qqr = zq; }
        a0 = a1; b0 = b1;
        if (c < 6) { a1 = a2; b1 = b2; }
    }

    // phase 3: all 64 bins' scalar math lane-parallel (lane = bin)
    float wl = widths[lane];
    float tt = wl * fmaf(wl, qqr, 2.f * d0r);     // n2 increment of bin `lane`
    float incl = incl_scan(tt);
    float n2L = fmaxf(n2_0 + (incl - tt), 0.f);   // left-boundary norm^2
    float n2R = fmaxf(n2_0 + incl, 0.f);          // right-boundary norm^2
    float rrR = __builtin_amdgcn_sqrtf(n2R);
    float numerR = rrR * __expf(bsum - rrR);
    // numerL = numerR of lane-1 via DPP wave_shr:1 (lane 0 patched below)
    float numerL = __int_as_float(
        __builtin_amdgcn_update_dpp(0, __float_as_int(numerR), 0x138, 0xF, 0xF, true));
    numerL = (lane == 0) ? numer0 : numerL;
    float pd = fmaf(wl, qqr, d0r);                // dot1 = d0 + w*qq
    float term = numerR * __builtin_amdgcn_rcpf(pd + EPSF)
               - numerL * __builtin_amdgcn_rcpf(d0r + EPSF);
    float acc = reduce1(term);

    table[(size_t)p * BB + lane] = make_float4(n2L, d0r, qqr, bsum);

    if (lane == 0) bacc[wid] = (double)acc;
    __syncthreads();
    if (threadIdx.x == 0)
        atomicAdd(acc_out, bacc[0] + bacc[1] + bacc[2] + bacc[3]);
}

__global__ __launch_bounds__(256) void k_events(
    const float* __restrict__ times, const int* __restrict__ epid,
    const float* __restrict__ bounds, const float* __restrict__ innerPad,
    const float4* __restrict__ table, double* __restrict__ acc_out) {
    __shared__ float si[64];
    __shared__ float sb[BB + 1];
    __shared__ double wacc[4];
    int tid = threadIdx.x;
    if (tid < 64) si[tid] = innerPad[tid];
    if (tid <= BB) sb[tid] = bounds[tid];
    __syncthreads();
    int g = (blockIdx.x * 256 + tid) * 2;          // 2 events per thread
    float2 tm2 = *(const float2*)(times + g);
    int2 pd2 = *(const int2*)(epid + g);
    float tms[2] = {tm2.x, tm2.y};
    int pids[2] = {pd2.x, pd2.y};
    int cc[2];
    float rem[2];
#pragma unroll
    for (int k = 0; k < 2; k++) {
        int c = 0;  // searchsorted(inner, tm, 'right') via binary search over padded 64
        float tm = tms[k];
#pragma unroll
        for (int s = 32; s >= 1; s >>= 1)
            if (si[c + s - 1] <= tm) c += s;
        cc[k] = c;
        rem[k] = tm - sb[c];
    }
    float4 e0 = table[(size_t)pids[0] * BB + cc[0]];
    float4 e1 = table[(size_t)pids[1] * BB + cc[1]];
    float eacc;
    {
        float d2 = fmaxf(fmaf(rem[0], fmaf(rem[0], e0.z, 2.f * e0.y), e0.x), 0.f);
        eacc = e0.w - __builtin_amdgcn_sqrtf(d2);
        d2 = fmaxf(fmaf(rem[1], fmaf(rem[1], e1.z, 2.f * e1.y), e1.x), 0.f);
        eacc += e1.w - __builtin_amdgcn_sqrtf(d2);
    }
    float val = reduce1(eacc);
    if ((tid & 63) == 0) wacc[tid >> 6] = (double)val;
    __syncthreads();
    if (tid == 0)
        atomicAdd(acc_out, -(wacc[0] + wacc[1] + wacc[2] + wacc[3]));
}

__global__ void k_finalize(const double* __restrict__ acc, float* __restrict__ out) {
    out[0] = (float)(*acc);
}

extern "C" void kernel_launch(void* const* d_in, const int* in_sizes, int n_in,
                              void* d_out, int out_size, void* d_ws, size_t ws_size,
                              hipStream_t stream) {
    const float* x0     = (const float*)d_in[0];
    const float* v      = (const float*)d_in[1];
    const float* beta   = (const float*)d_in[2];
    const float* brw    = (const float*)d_in[3];
    const float* etimes = (const float*)d_in[4];
    const int*   pairs  = (const int*)d_in[5];
    const int*   epid   = (const int*)d_in[6];

    char* ws = (char*)d_ws;
    double* acc     = (double*)ws;
    int* cnt        = (int*)(ws + 1024);
    int* cursor     = (int*)(ws + 9216);
    int* perm       = (int*)(ws + 17408);
    float* bounds   = (float*)(ws + 82944);
    float* widths   = (float*)(ws + 83456);
    float* innerPad = (float*)(ws + 83968);
    float4* table   = (float4*)(ws + 84480);
    unsigned* vh32  = (unsigned*)(ws + 84480 + (size_t)PP * BB * 16);

    hipLaunchKernelGGL(k_bounds, dim3(9), dim3(64), 0, stream, brw, bounds, widths,
                       innerPad, cnt, acc);
    hipLaunchKernelGGL(k_convert, dim3(NN / 4), dim3(256), 0, stream, v, vh32);
    hipLaunchKernelGGL(k_hist2, dim3(PP / 256), dim3(256), 0, stream, pairs, cnt);
    hipLaunchKernelGGL(k_scan2, dim3(1), dim3(1024), 0, stream, cnt, cursor);
    hipLaunchKernelGGL(k_scatter2, dim3(PP / 256), dim3(256), 0, stream, pairs, cursor, perm);
    hipLaunchKernelGGL(k_pairs, dim3(PP / 4), dim3(256), 0, stream, x0, (const uint4*)vh32,
                       beta, pairs, perm, widths, table, acc);
    hipLaunchKernelGGL(k_events, dim3(TT / 512), dim3(256), 0, stream, etimes, epid,
                       bounds, innerPad, table, acc);
    hipLaunchKernelGGL(k_finalize, dim3(1), dim3(1), 0, stream, acc, (float*)d_out);
}

// Round 12
// 103.223 us; speedup vs baseline: 1.0010x; 1.0010x over previous
//
#include <hip/hip_runtime.h>

#define NN 2048
#define DD 64
#define BB 64
#define PP 16384
#define TT 262144
#define EPSF 1e-6f
#define SS ((size_t)NN * DD)  // floats between consecutive bins of v (bin-major)

// ---------------- ws layout (bytes) ----------------
// 0        : double acc
// 1024     : int cnt[2048]     (node-i histogram)
// 9216     : int cursor[2048]
// 17408    : int perm[PP]      (pair ids sorted by node i)
// 82944    : float bounds[65]
// 83456    : float widths[64]
// 83968    : float innerPad[64]
// 84480    : float4 table[PP*BB]  (n2_left, d0, qq, bsum) = 16.78 MB
// 16861696 : ushort vh[NN*BB*DD]  (bf16 node-major v)      = 16.78 MB

typedef unsigned uv2 __attribute__((ext_vector_type(2)));
using bf16x8 = __attribute__((ext_vector_type(8))) short;
using f32x4v = __attribute__((ext_vector_type(4))) float;

template <int CTRL, int RM = 0xF, bool BC = true>
__device__ __forceinline__ float dpp_add(float x) {
    int y = __builtin_amdgcn_update_dpp(0, __float_as_int(x), CTRL, RM, 0xF, BC);
    return x + __int_as_float(y);
}

template <int PAT>
__device__ __forceinline__ float swz_add(float x) {
    return x + __int_as_float(__builtin_amdgcn_ds_swizzle(__float_as_int(x), PAT));
}

__device__ __forceinline__ float xor16_add(float x) {
#if __has_builtin(__builtin_amdgcn_permlane16_swap)
    uv2 r = __builtin_amdgcn_permlane16_swap(__float_as_uint(x), __float_as_uint(x),
                                             false, false);
    return __uint_as_float(r.x) + __uint_as_float(r.y);
#else
    return swz_add<0x401F>(x);
#endif
}
__device__ __forceinline__ float xor32_add(float x) {
#if __has_builtin(__builtin_amdgcn_permlane32_swap)
    uv2 r = __builtin_amdgcn_permlane32_swap(__float_as_uint(x), __float_as_uint(x),
                                             false, false);
    return __uint_as_float(r.x) + __uint_as_float(r.y);
#else
    return x + __shfl_xor(x, 32, 64);
#endif
}

// full 64-lane sum, result on all lanes
__device__ __forceinline__ float reduce1(float a) {
    a = dpp_add<0xB1>(a);     // quad_perm xor1
    a = dpp_add<0x4E>(a);     // quad_perm xor2
    a = dpp_add<0x141>(a);    // row_half_mirror (completes sum of 8)
    a = swz_add<0x201F>(a);   // xor8
    a = xor16_add(a);
    a = xor32_add(a);
    return a;
}

// 64-lane inclusive prefix sum (canonical 6-DPP scan)
__device__ __forceinline__ float incl_scan(float x) {
    x = dpp_add<0x111>(x);             // row_shr:1
    x = dpp_add<0x112>(x);             // row_shr:2
    x = dpp_add<0x114>(x);             // row_shr:4
    x = dpp_add<0x118>(x);             // row_shr:8
    x = dpp_add<0x142, 0xA, false>(x); // row_bcast:15 -> rows 1,3
    x = dpp_add<0x143, 0xC, false>(x); // row_bcast:31 -> rows 2,3
    return x;
}

__device__ __forceinline__ unsigned short f2bf(float f) {  // RNE
    unsigned u = __float_as_uint(f);
    unsigned r = (u + 0x7FFFu + ((u >> 16) & 1u)) >> 16;
    return (unsigned short)r;
}
__device__ __forceinline__ float bf_lo(unsigned u) { return __uint_as_float(u << 16); }
__device__ __forceinline__ float bf_hi(unsigned u) { return __uint_as_float(u & 0xFFFF0000u); }

__device__ __forceinline__ unsigned cvt_pk_bf(float lo, float hi) {
    unsigned r;
    asm("v_cvt_pk_bf16_f32 %0, %1, %2" : "=v"(r) : "v"(lo), "v"(hi));
    return r;  // lo16 = bf16(lo), hi16 = bf16(hi) (order-consistent across all uses)
}
__device__ __forceinline__ float bpermf(float v, int srclane) {
    return __int_as_float(__builtin_amdgcn_ds_bpermute(srclane << 2, __float_as_int(v)));
}

__global__ void k_bounds(const float* __restrict__ brw, float* __restrict__ bounds,
                         float* __restrict__ widths, float* __restrict__ innerPad,
                         int* __restrict__ cnt, double* __restrict__ acc) {
    if (blockIdx.x != 0) {
        int t = (blockIdx.x - 1) * 64 + threadIdx.x;  // 0..511
#pragma unroll
        for (int k = 0; k < 4; k++) cnt[t * 4 + k] = 0;
        if (blockIdx.x == 1 && threadIdx.x == 0) acc[0] = 0.0;
        return;
    }
    int lane = threadIdx.x;  // 64 threads
    float w = brw[lane];
    float m = w;
#pragma unroll
    for (int s = 32; s >= 1; s >>= 1) m = fmaxf(m, __shfl_xor(m, s, 64));
    float e = expf(w - m);
    float tot = e;
#pragma unroll
    for (int s = 32; s >= 1; s >>= 1) tot += __shfl_xor(tot, s, 64);
    float sm = e / tot;
    float c = sm;
#pragma unroll
    for (int off = 1; off < 64; off <<= 1) {
        float t = __shfl_up(c, off, 64);
        if (lane >= off) c += t;
    }
    float cexcl = __shfl_up(c, 1, 64);
    if (lane == 0) cexcl = 0.f;
    if (lane == 0) bounds[0] = 0.f;
    bounds[lane + 1] = c;
    widths[lane] = c - cexcl;
    innerPad[lane] = (lane == 63) ? 3.4e38f : c;
}

// v[b][n][d] fp32 -> vh[n][b][d] bf16 (node-major: one node = contiguous 8KB)
__global__ __launch_bounds__(256) void k_convert(const float* __restrict__ v,
                                                 unsigned* __restrict__ vh32) {
    int wid = threadIdx.x >> 6, lane = threadIdx.x & 63;
    int n = blockIdx.x * 4 + wid;
    int sub = lane >> 5;
    int dp = (lane & 31) * 2;
    unsigned* __restrict__ dst = vh32 + ((size_t)n * BB * DD) / 2;
#pragma unroll
    for (int c = 0; c < 32; c++) {
        int b = c * 2 + sub;
        float2 f = *(const float2*)(v + (size_t)b * SS + (size_t)n * DD + dp);
        unsigned pk = (unsigned)f2bf(f.x) | ((unsigned)f2bf(f.y) << 16);
        dst[(b * DD + dp) / 2] = pk;
    }
}

__global__ void k_hist2(const int* __restrict__ pairs, int* __restrict__ cnt) {
    int t = blockIdx.x * 256 + threadIdx.x;
    atomicAdd(&cnt[pairs[t]], 1);
}

__global__ __launch_bounds__(1024) void k_scan2(const int* __restrict__ cnt,
                                                int* __restrict__ cursor) {
    __shared__ int waveTot[16];
    __shared__ int waveOff[16];
    int tid = threadIdx.x;
    int a = cnt[tid * 2], b = cnt[tid * 2 + 1];
    int s = a + b;
    int lane = tid & 63, wid = tid >> 6;
    int incl = s;
#pragma unroll
    for (int off = 1; off < 64; off <<= 1) {
        int t2 = __shfl_up(incl, off, 64);
        if (lane >= off) incl += t2;
    }
    if (lane == 63) waveTot[wid] = incl;
    __syncthreads();
    if (tid == 0) {
        int r = 0;
        for (int w = 0; w < 16; w++) { waveOff[w] = r; r += waveTot[w]; }
    }
    __syncthreads();
    int run = waveOff[wid] + (incl - s);
    cursor[tid * 2] = run;
    cursor[tid * 2 + 1] = run + a;
}

__global__ void k_scatter2(const int* __restrict__ pairs, int* __restrict__ cursor,
                           int* __restrict__ perm) {
    int t = blockIdx.x * 256 + threadIdx.x;
    int pos = atomicAdd(&cursor[pairs[t]], 1);
    perm[pos] = t;
}

__global__ __launch_bounds__(256) void k_pairs(
    const float* __restrict__ x0, const uint4* __restrict__ vh4,
    const float* __restrict__ beta, const int* __restrict__ pairs,
    const int* __restrict__ perm, const float* __restrict__ widths,
    float4* __restrict__ table, double* __restrict__ acc_out) {
    __shared__ double bacc[4];
    const int wid = threadIdx.x >> 6;
    const int lane = threadIdx.x & 63;
    const int bid = blockIdx.x;
    const int vb = ((bid & 7) << 9) | (bid >> 3);  // XCD-contiguous p-ranges
    const int p = perm[vb * 4 + wid];

    const int i = pairs[p];
    const int j = pairs[PP + p];
    const float bsum = beta[i] + beta[j];

    float dx0 = x0[i * DD + lane] - x0[j * DD + lane];  // lane = dim
    float n2_0 = reduce1(dx0 * dx0);
    float rr0 = __builtin_amdgcn_sqrtf(n2_0);
    float numer0 = rr0 * __expf(bsum - rr0);

    // per-lane width table: wv[tm][r] = widths[16*tm + (lane>>4)*4 + r]
    float wv[4][4];
#pragma unroll
    for (int tm = 0; tm < 4; tm++)
#pragma unroll
        for (int r = 0; r < 4; r++)
            wv[tm][r] = widths[16 * tm + (lane >> 4) * 4 + r];

    // ---- 16-deep load burst: frag (t,kb) covers bins 16t+(lane&15), dims kb*32+(lane>>4)*8..+7
    const int laneterm = (lane & 15) * 8 + (lane >> 4);
    const uint4* __restrict__ Vi = vh4 + (size_t)i * 512 + laneterm;
    const uint4* __restrict__ Vj = vh4 + (size_t)j * 512 + laneterm;
    uint4 ra[8], rb[8];
#pragma unroll
    for (int t = 0; t < 4; t++)
#pragma unroll
        for (int kb = 0; kb < 2; kb++) {
            ra[t * 2 + kb] = Vi[t * 128 + kb * 4];
            rb[t * 2 + kb] = Vj[t * 128 + kb * 4];
        }

    // ---- dv fragments in bf16 (A-row and B-col layouts coincide for Gram)
    bf16x8 F[8];
#pragma unroll
    for (int f = 0; f < 8; f++) {
        uint4 q;
        q.x = cvt_pk_bf(bf_lo(ra[f].x) - bf_lo(rb[f].x), bf_hi(ra[f].x) - bf_hi(rb[f].x));
        q.y = cvt_pk_bf(bf_lo(ra[f].y) - bf_lo(rb[f].y), bf_hi(ra[f].y) - bf_hi(rb[f].y));
        q.z = cvt_pk_bf(bf_lo(ra[f].z) - bf_lo(rb[f].z), bf_hi(ra[f].z) - bf_hi(rb[f].z));
        q.w = cvt_pk_bf(bf_lo(ra[f].w) - bf_lo(rb[f].w), bf_hi(ra[f].w) - bf_hi(rb[f].w));
        union { uint4 u; bf16x8 s; } cv;
        cv.u = q;
        F[f] = cv.s;
    }

    // ---- A_x: row 0 = dx0 (bf16), rows 1-15 = 0  (for c0 = D·dx0 via MFMA)
    bf16x8 AX[2];
#pragma unroll
    for (int kb = 0; kb < 2; kb++) {
        unsigned u[4];
#pragma unroll
        for (int c2 = 0; c2 < 4; c2++) {
            int k0 = kb * 32 + ((lane >> 4) << 3) + c2 * 2;
            u[c2] = cvt_pk_bf(bpermf(dx0, k0), bpermf(dx0, k0 + 1));
        }
        uint4 q;
        bool z = (lane & 15) != 0;
        q.x = z ? 0u : u[0]; q.y = z ? 0u : u[1];
        q.z = z ? 0u : u[2]; q.w = z ? 0u : u[3];
        union { uint4 uu; bf16x8 s; } cv;
        cv.uu = q;
        AX[kb] = cv.s;
    }

    // ---- G upper-triangle tiles via MFMA (G symmetric: only tm<=tn needed)
    f32x4v g00 = {0.f, 0.f, 0.f, 0.f}, g01 = g00, g02 = g00, g03 = g00;
    f32x4v g11 = g00, g12 = g00, g13 = g00, g22 = g00, g23 = g00, g33 = g00;
#define GMM(acc, ta, tb)                                                              \
    acc = __builtin_amdgcn_mfma_f32_16x16x32_bf16(F[(ta)*2 + 0], F[(tb)*2 + 0], acc, 0, 0, 0); \
    acc = __builtin_amdgcn_mfma_f32_16x16x32_bf16(F[(ta)*2 + 1], F[(tb)*2 + 1], acc, 0, 0, 0);
    GMM(g00, 0, 0) GMM(g01, 0, 1) GMM(g02, 0, 2) GMM(g03, 0, 3)
    GMM(g11, 1, 1) GMM(g12, 1, 2) GMM(g13, 1, 3)
    GMM(g22, 2, 2) GMM(g23, 2, 3) GMM(g33, 3, 3)
    // c0 row-vector: C[0][n] = dx0 · dv_n
    f32x4v c0a0 = g00; c0a0 = {0.f, 0.f, 0.f, 0.f};
    f32x4v c0a1 = c0a0, c0a2 = c0a0, c0a3 = c0a0;
    GMM(c0a0, /*A_x*/ 0, 0)  // placeholder removed below
#undef GMM
    // redo c0 with AX operand (separate macro to keep A=AX)
    c0a0 = {0.f, 0.f, 0.f, 0.f}; c0a1 = c0a0; c0a2 = c0a0; c0a3 = c0a0;
#define CMM(acc, tb)                                                                   \
    acc = __builtin_amdgcn_mfma_f32_16x16x32_bf16(AX[0], F[(tb)*2 + 0], acc, 0, 0, 0); \
    acc = __builtin_amdgcn_mfma_f32_16x16x32_bf16(AX[1], F[(tb)*2 + 1], acc, 0, 0, 0);
    CMM(c0a0, 0) CMM(c0a1, 1) CMM(c0a2, 2) CMM(c0a3, 3)
#undef CMM

    // ---- c0 broadcast: value lives on lanes 0-15 (row 0, reg 0), col = lane&15
    float c0v = 0.f;
    {
        float b0 = bpermf(c0a0[0], lane & 15);
        float b1 = bpermf(c0a1[0], lane & 15);
        float b2 = bpermf(c0a2[0], lane & 15);
        float b3 = bpermf(c0a3[0], lane & 15);
        int g = lane >> 4;
        c0v = (g == 0) ? b0 : (g == 1) ? b1 : (g == 2) ? b2 : b3;
    }

    // ---- masked column sums: S[b] = sum_{b'<b} w[b'] G[b'][b];  qq[b] = G[b][b]
    const int nl = lane & 15;
    const int mb = (lane >> 4) * 4;
    float Sv = 0.f, qv = 0.f;
#define OFFT(gt, t_) (wv[t_][0] * gt[0] + wv[t_][1] * gt[1] + wv[t_][2] * gt[2] + wv[t_][3] * gt[3])
#define DIAG(d, t_)                                              \
    sp += (mb + 0 < nl) ? wv[t_][0] * d[0] : 0.f;                \
    sp += (mb + 1 < nl) ? wv[t_][1] * d[1] : 0.f;                \
    sp += (mb + 2 < nl) ? wv[t_][2] * d[2] : 0.f;                \
    sp += (mb + 3 < nl) ? wv[t_][3] * d[3] : 0.f;                \
    qp += (mb + 0 == nl) ? d[0] : 0.f;                           \
    qp += (mb + 1 == nl) ? d[1] : 0.f;                           \
    qp += (mb + 2 == nl) ? d[2] : 0.f;                           \
    qp += (mb + 3 == nl) ? d[3] : 0.f;
#define FINTN(t_)                                                \
    sp = xor16_add(sp); sp = xor32_add(sp);                      \
    qp = xor16_add(qp); qp = xor32_add(qp);                      \
    if ((lane >> 4) == t_) { Sv = sp; qv = qp; }
    {
        float sp = 0.f, qp = 0.f;
        DIAG(g00, 0) FINTN(0)
    }
    {
        float sp = OFFT(g01, 0), qp = 0.f;
        DIAG(g11, 1) FINTN(1)
    }
    {
        float sp = OFFT(g02, 0) + OFFT(g12, 1), qp = 0.f;
        DIAG(g22, 2) FINTN(2)
    }
    {
        float sp = OFFT(g03, 0) + OFFT(g13, 1) + OFFT(g23, 2), qp = 0.f;
        DIAG(g33, 3) FINTN(3)
    }
#undef OFFT
#undef DIAG
#undef FINTN

    float d0r = c0v + Sv;
    float qqr = qv;

    // ---- phase 3: all 64 bins' scalar math lane-parallel (lane = bin)
    float wl = widths[lane];
    float tt = wl * fmaf(wl, qqr, 2.f * d0r);
    float incl = incl_scan(tt);
    float n2L = fmaxf(n2_0 + (incl - tt), 0.f);
    float n2R = fmaxf(n2_0 + incl, 0.f);
    float rrR = __builtin_amdgcn_sqrtf(n2R);
    float numerR = rrR * __expf(bsum - rrR);
    float numerL = __int_as_float(
        __builtin_amdgcn_update_dpp(0, __float_as_int(numerR), 0x138, 0xF, 0xF, true));
    numerL = (lane == 0) ? numer0 : numerL;
    float pd = fmaf(wl, qqr, d0r);
    float term = numerR * __builtin_amdgcn_rcpf(pd + EPSF)
               - numerL * __builtin_amdgcn_rcpf(d0r + EPSF);
    float acc = reduce1(term);

    table[(size_t)p * BB + lane] = make_float4(n2L, d0r, qqr, bsum);

    if (lane == 0) bacc[wid] = (double)acc;
    __syncthreads();
    if (threadIdx.x == 0)
        atomicAdd(acc_out, bacc[0] + bacc[1] + bacc[2] + bacc[3]);
}

__global__ __launch_bounds__(256) void k_events(
    const float* __restrict__ times, const int* __restrict__ epid,
    const float* __restrict__ bounds, const float* __restrict__ innerPad,
    const float4* __restrict__ table, double* __restrict__ acc_out) {
    __shared__ float si[64];
    __shared__ float sb[BB + 1];
    __shared__ double wacc[4];
    int tid = threadIdx.x;
    if (tid < 64) si[tid] = innerPad[tid];
    if (tid <= BB) sb[tid] = bounds[tid];
    __syncthreads();
    int g = (blockIdx.x * 256 + tid) * 2;
    float2 tm2 = *(const float2*)(times + g);
    int2 pd2 = *(const int2*)(epid + g);
    float tms[2] = {tm2.x, tm2.y};
    int pids[2] = {pd2.x, pd2.y};
    int cc[2];
    float rem[2];
#pragma unroll
    for (int k = 0; k < 2; k++) {
        int c = 0;
        float tm = tms[k];
#pragma unroll
        for (int s = 32; s >= 1; s >>= 1)
            if (si[c + s - 1] <= tm) c += s;
        cc[k] = c;
        rem[k] = tm - sb[c];
    }
    float4 e0 = table[(size_t)pids[0] * BB + cc[0]];
    float4 e1 = table[(size_t)pids[1] * BB + cc[1]];
    float eacc;
    {
        float d2 = fmaxf(fmaf(rem[0], fmaf(rem[0], e0.z, 2.f * e0.y), e0.x), 0.f);
        eacc = e0.w - __builtin_amdgcn_sqrtf(d2);
        d2 = fmaxf(fmaf(rem[1], fmaf(rem[1], e1.z, 2.f * e1.y), e1.x), 0.f);
        eacc += e1.w - __builtin_amdgcn_sqrtf(d2);
    }
    float val = reduce1(eacc);
    if ((tid & 63) == 0) wacc[tid >> 6] = (double)val;
    __syncthreads();
    if (tid == 0)
        atomicAdd(acc_out, -(wacc[0] + wacc[1] + wacc[2] + wacc[3]));
}

__global__ void k_finalize(const double* __restrict__ acc, float* __restrict__ out) {
    out[0] = (float)(*acc);
}

extern "C" void kernel_launch(void* const* d_in, const int* in_sizes, int n_in,
                              void* d_out, int out_size, void* d_ws, size_t ws_size,
                              hipStream_t stream) {
    const float* x0     = (const float*)d_in[0];
    const float* v      = (const float*)d_in[1];
    const float* beta   = (const float*)d_in[2];
    const float* brw    = (const float*)d_in[3];
    const float* etimes = (const float*)d_in[4];
    const int*   pairs  = (const int*)d_in[5];
    const int*   epid   = (const int*)d_in[6];

    char* ws = (char*)d_ws;
    double* acc     = (double*)ws;
    int* cnt        = (int*)(ws + 1024);
    int* cursor     = (int*)(ws + 9216);
    int* perm       = (int*)(ws + 17408);
    float* bounds   = (float*)(ws + 82944);
    float* widths   = (float*)(ws + 83456);
    float* innerPad = (float*)(ws + 83968);
    float4* table   = (float4*)(ws + 84480);
    unsigned* vh32  = (unsigned*)(ws + 84480 + (size_t)PP * BB * 16);

    hipLaunchKernelGGL(k_bounds, dim3(9), dim3(64), 0, stream, brw, bounds, widths,
                       innerPad, cnt, acc);
    hipLaunchKernelGGL(k_convert, dim3(NN / 4), dim3(256), 0, stream, v, vh32);
    hipLaunchKernelGGL(k_hist2, dim3(PP / 256), dim3(256), 0, stream, pairs, cnt);
    hipLaunchKernelGGL(k_scan2, dim3(1), dim3(1024), 0, stream, cnt, cursor);
    hipLaunchKernelGGL(k_scatter2, dim3(PP / 256), dim3(256), 0, stream, pairs, cursor, perm);
    hipLaunchKernelGGL(k_pairs, dim3(PP / 4), dim3(256), 0, stream, x0, (const uint4*)vh32,
                       beta, pairs, perm, widths, table, acc);
    hipLaunchKernelGGL(k_events, dim3(TT / 512), dim3(256), 0, stream, etimes, epid,
                       bounds, innerPad, table, acc);
    hipLaunchKernelGGL(k_finalize, dim3(1), dim3(1), 0, stream, acc, (float*)d_out);
}

// Round 13
// 78.736 us; speedup vs baseline: 1.3124x; 1.3110x over previous
//
#include <hip/hip_runtime.h>

#define NN 2048
#define DD 64
#define BB 64
#define PP 16384
#define TT 262144
#define EPSF 1e-6f
#define SS ((size_t)NN * DD)  // floats between consecutive bins of v (bin-major)

// ---------------- ws layout (bytes) ----------------
// 0        : double acc
// 1024     : int cnt[2048]     (node-i histogram)
// 9216     : int cursor[2048]
// 17408    : int perm[PP]      (pair ids sorted by node i)
// 82944    : float bounds[65]
// 83456    : float widths[64]
// 83968    : float innerPad[64]
// 84480    : float4 table[PP*BB]  (n2_left, d0, qq, bsum) = 16.78 MB
// 16861696 : ushort vh[NN*BB*DD]  (bf16 node-major v)      = 16.78 MB

typedef unsigned uv2 __attribute__((ext_vector_type(2)));
using bf16x8 = __attribute__((ext_vector_type(8))) short;
using f32x4v = __attribute__((ext_vector_type(4))) float;

template <int CTRL, int RM = 0xF, bool BC = true>
__device__ __forceinline__ float dpp_add(float x) {
    int y = __builtin_amdgcn_update_dpp(0, __float_as_int(x), CTRL, RM, 0xF, BC);
    return x + __int_as_float(y);
}

template <int PAT>
__device__ __forceinline__ float swz_add(float x) {
    return x + __int_as_float(__builtin_amdgcn_ds_swizzle(__float_as_int(x), PAT));
}

__device__ __forceinline__ float xor16_add(float x) {
#if __has_builtin(__builtin_amdgcn_permlane16_swap)
    uv2 r = __builtin_amdgcn_permlane16_swap(__float_as_uint(x), __float_as_uint(x),
                                             false, false);
    return __uint_as_float(r.x) + __uint_as_float(r.y);
#else
    return swz_add<0x401F>(x);
#endif
}
__device__ __forceinline__ float xor32_add(float x) {
#if __has_builtin(__builtin_amdgcn_permlane32_swap)
    uv2 r = __builtin_amdgcn_permlane32_swap(__float_as_uint(x), __float_as_uint(x),
                                             false, false);
    return __uint_as_float(r.x) + __uint_as_float(r.y);
#else
    return x + __shfl_xor(x, 32, 64);
#endif
}

// full 64-lane sum, result on all lanes
__device__ __forceinline__ float reduce1(float a) {
    a = dpp_add<0xB1>(a);
    a = dpp_add<0x4E>(a);
    a = dpp_add<0x141>(a);
    a = swz_add<0x201F>(a);
    a = xor16_add(a);
    a = xor32_add(a);
    return a;
}

// 64-lane inclusive prefix sum
__device__ __forceinline__ float incl_scan(float x) {
    x = dpp_add<0x111>(x);
    x = dpp_add<0x112>(x);
    x = dpp_add<0x114>(x);
    x = dpp_add<0x118>(x);
    x = dpp_add<0x142, 0xA, false>(x);
    x = dpp_add<0x143, 0xC, false>(x);
    return x;
}

__device__ __forceinline__ unsigned short f2bf(float f) {  // RNE
    unsigned u = __float_as_uint(f);
    unsigned r = (u + 0x7FFFu + ((u >> 16) & 1u)) >> 16;
    return (unsigned short)r;
}
__device__ __forceinline__ float bf_lo(unsigned u) { return __uint_as_float(u << 16); }
__device__ __forceinline__ float bf_hi(unsigned u) { return __uint_as_float(u & 0xFFFF0000u); }

__device__ __forceinline__ unsigned cvt_pk_bf(float lo, float hi) {
    unsigned r;
    asm("v_cvt_pk_bf16_f32 %0, %1, %2" : "=v"(r) : "v"(lo), "v"(hi));
    return r;
}
__device__ __forceinline__ float bpermf(float v, int srclane) {
    return __int_as_float(__builtin_amdgcn_ds_bpermute(srclane << 2, __float_as_int(v)));
}

__global__ void k_bounds(const float* __restrict__ brw, float* __restrict__ bounds,
                         float* __restrict__ widths, float* __restrict__ innerPad,
                         int* __restrict__ cnt, double* __restrict__ acc) {
    if (blockIdx.x != 0) {
        int t = (blockIdx.x - 1) * 64 + threadIdx.x;
#pragma unroll
        for (int k = 0; k < 4; k++) cnt[t * 4 + k] = 0;
        if (blockIdx.x == 1 && threadIdx.x == 0) acc[0] = 0.0;
        return;
    }
    int lane = threadIdx.x;
    float w = brw[lane];
    float m = w;
#pragma unroll
    for (int s = 32; s >= 1; s >>= 1) m = fmaxf(m, __shfl_xor(m, s, 64));
    float e = expf(w - m);
    float tot = e;
#pragma unroll
    for (int s = 32; s >= 1; s >>= 1) tot += __shfl_xor(tot, s, 64);
    float sm = e / tot;
    float c = sm;
#pragma unroll
    for (int off = 1; off < 64; off <<= 1) {
        float t = __shfl_up(c, off, 64);
        if (lane >= off) c += t;
    }
    float cexcl = __shfl_up(c, 1, 64);
    if (lane == 0) cexcl = 0.f;
    if (lane == 0) bounds[0] = 0.f;
    bounds[lane + 1] = c;
    widths[lane] = c - cexcl;
    innerPad[lane] = (lane == 63) ? 3.4e38f : c;
}

// v[b][n][d] fp32 -> vh[n][b][d] bf16
__global__ __launch_bounds__(256) void k_convert(const float* __restrict__ v,
                                                 unsigned* __restrict__ vh32) {
    int wid = threadIdx.x >> 6, lane = threadIdx.x & 63;
    int n = blockIdx.x * 4 + wid;
    int sub = lane >> 5;
    int dp = (lane & 31) * 2;
    unsigned* __restrict__ dst = vh32 + ((size_t)n * BB * DD) / 2;
#pragma unroll
    for (int c = 0; c < 32; c++) {
        int b = c * 2 + sub;
        float2 f = *(const float2*)(v + (size_t)b * SS + (size_t)n * DD + dp);
        unsigned pk = (unsigned)f2bf(f.x) | ((unsigned)f2bf(f.y) << 16);
        dst[(b * DD + dp) / 2] = pk;
    }
}

__global__ void k_hist2(const int* __restrict__ pairs, int* __restrict__ cnt) {
    int t = blockIdx.x * 256 + threadIdx.x;
    atomicAdd(&cnt[pairs[t]], 1);
}

__global__ __launch_bounds__(1024) void k_scan2(const int* __restrict__ cnt,
                                                int* __restrict__ cursor) {
    __shared__ int waveTot[16];
    __shared__ int waveOff[16];
    int tid = threadIdx.x;
    int a = cnt[tid * 2], b = cnt[tid * 2 + 1];
    int s = a + b;
    int lane = tid & 63, wid = tid >> 6;
    int incl = s;
#pragma unroll
    for (int off = 1; off < 64; off <<= 1) {
        int t2 = __shfl_up(incl, off, 64);
        if (lane >= off) incl += t2;
    }
    if (lane == 63) waveTot[wid] = incl;
    __syncthreads();
    if (tid == 0) {
        int r = 0;
        for (int w = 0; w < 16; w++) { waveOff[w] = r; r += waveTot[w]; }
    }
    __syncthreads();
    int run = waveOff[wid] + (incl - s);
    cursor[tid * 2] = run;
    cursor[tid * 2 + 1] = run + a;
}

__global__ void k_scatter2(const int* __restrict__ pairs, int* __restrict__ cursor,
                           int* __restrict__ perm) {
    int t = blockIdx.x * 256 + threadIdx.x;
    int pos = atomicAdd(&cursor[pairs[t]], 1);
    perm[pos] = t;
}

// 4 pairs per wave, software-pipelined: pair k+1's 16-load burst issues right
// after pair k's raw regs are converted to bf16 fragments; MFMA+phase3 of pair
// k covers the gather latency of pair k+1.
__global__ __launch_bounds__(256, 2) void k_pairs(
    const float* __restrict__ x0, const uint4* __restrict__ vh4,
    const float* __restrict__ beta, const int* __restrict__ pairs,
    const int* __restrict__ perm, const float* __restrict__ widths,
    float4* __restrict__ table, double* __restrict__ acc_out) {
    __shared__ double bacc[4];
    const int wid = threadIdx.x >> 6;
    const int lane = threadIdx.x & 63;
    const int bid = blockIdx.x;
    const int vb = ((bid & 7) << 7) | (bid >> 3);  // XCD swizzle over 1024 blocks
    const int pbase = (vb * 4 + wid) * 4;

    // pair ids for all 4 pairs (wave-uniform)
    int pk[4], ik[4], jk[4];
    float bs[4];
#pragma unroll
    for (int k = 0; k < 4; k++) pk[k] = perm[pbase + k];
#pragma unroll
    for (int k = 0; k < 4; k++) {
        ik[k] = pairs[pk[k]];
        jk[k] = pairs[PP + pk[k]];
    }
#pragma unroll
    for (int k = 0; k < 4; k++) bs[k] = beta[ik[k]] + beta[jk[k]];

    // per-lane width fragment rows (invariant across pairs)
    float wv[4][4];
#pragma unroll
    for (int tm = 0; tm < 4; tm++)
#pragma unroll
        for (int r = 0; r < 4; r++)
            wv[tm][r] = widths[16 * tm + (lane >> 4) * 4 + r];
    const float wl = widths[lane];
    const int laneterm = (lane & 15) * 8 + (lane >> 4);
    const int nl = lane & 15;
    const int mb = (lane >> 4) * 4;

    // single staging buffer, reused across pairs (WAR enforces order)
    uint4 ra[8], rb[8];
    float xiv, xjv;

#define ISSUE(k_)                                                            \
    {                                                                        \
        const uint4* Vi = vh4 + (size_t)ik[k_] * 512 + laneterm;             \
        const uint4* Vj = vh4 + (size_t)jk[k_] * 512 + laneterm;             \
        _Pragma("unroll") for (int t = 0; t < 4; t++) {                      \
            ra[t * 2 + 0] = Vi[t * 128];                                     \
            ra[t * 2 + 1] = Vi[t * 128 + 4];                                 \
            rb[t * 2 + 0] = Vj[t * 128];                                     \
            rb[t * 2 + 1] = Vj[t * 128 + 4];                                 \
        }                                                                    \
        xiv = x0[ik[k_] * DD + lane];                                        \
        xjv = x0[jk[k_] * DD + lane];                                        \
    }

    ISSUE(0)

    double accd = 0.0;

#pragma unroll
    for (int k = 0; k < 4; k++) {
        const float bsum = bs[k];
        // ---- convert raw burst -> fragments (consumes ra/rb, then they're free)
        float dx0 = xiv - xjv;
        float n2_0 = reduce1(dx0 * dx0);
        float rr0 = __builtin_amdgcn_sqrtf(n2_0);
        float numer0 = rr0 * __expf(bsum - rr0);

        bf16x8 F[8];
#pragma unroll
        for (int f = 0; f < 8; f++) {
            uint4 q;
            q.x = cvt_pk_bf(bf_lo(ra[f].x) - bf_lo(rb[f].x), bf_hi(ra[f].x) - bf_hi(rb[f].x));
            q.y = cvt_pk_bf(bf_lo(ra[f].y) - bf_lo(rb[f].y), bf_hi(ra[f].y) - bf_hi(rb[f].y));
            q.z = cvt_pk_bf(bf_lo(ra[f].z) - bf_lo(rb[f].z), bf_hi(ra[f].z) - bf_hi(rb[f].z));
            q.w = cvt_pk_bf(bf_lo(ra[f].w) - bf_lo(rb[f].w), bf_hi(ra[f].w) - bf_hi(rb[f].w));
            union { uint4 u; bf16x8 s; } cv;
            cv.u = q;
            F[f] = cv.s;
        }

        // ---- issue next pair's burst into the (now free) staging regs
        if (k < 3) {
            if (k == 0) ISSUE(1)
            if (k == 1) ISSUE(2)
            if (k == 2) ISSUE(3)
        }

        // ---- A_x fragment: row 0 = dx0 (bf16)
        bf16x8 AX[2];
#pragma unroll
        for (int kb = 0; kb < 2; kb++) {
            unsigned u[4];
#pragma unroll
            for (int c2 = 0; c2 < 4; c2++) {
                int k0 = kb * 32 + ((lane >> 4) << 3) + c2 * 2;
                u[c2] = cvt_pk_bf(bpermf(dx0, k0), bpermf(dx0, k0 + 1));
            }
            uint4 q;
            bool z = (lane & 15) != 0;
            q.x = z ? 0u : u[0]; q.y = z ? 0u : u[1];
            q.z = z ? 0u : u[2]; q.w = z ? 0u : u[3];
            union { uint4 uu; bf16x8 s; } cv;
            cv.uu = q;
            AX[kb] = cv.s;
        }

        // ---- Gram upper-triangle via MFMA
        f32x4v g00 = {0.f, 0.f, 0.f, 0.f}, g01 = g00, g02 = g00, g03 = g00;
        f32x4v g11 = g00, g12 = g00, g13 = g00, g22 = g00, g23 = g00, g33 = g00;
#define GMM(acc, ta, tb)                                                                       \
    acc = __builtin_amdgcn_mfma_f32_16x16x32_bf16(F[(ta)*2 + 0], F[(tb)*2 + 0], acc, 0, 0, 0); \
    acc = __builtin_amdgcn_mfma_f32_16x16x32_bf16(F[(ta)*2 + 1], F[(tb)*2 + 1], acc, 0, 0, 0);
        GMM(g00, 0, 0) GMM(g01, 0, 1) GMM(g02, 0, 2) GMM(g03, 0, 3)
        GMM(g11, 1, 1) GMM(g12, 1, 2) GMM(g13, 1, 3)
        GMM(g22, 2, 2) GMM(g23, 2, 3) GMM(g33, 3, 3)
#undef GMM
        // c0 row-vector: reuse one accumulator sequentially (saves VGPRs)
        float c00, c01, c02, c03;
        {
            f32x4v ca = {0.f, 0.f, 0.f, 0.f};
#define CMM(tb)                                                                        \
    ca = __builtin_amdgcn_mfma_f32_16x16x32_bf16(AX[0], F[(tb)*2 + 0], ca, 0, 0, 0);  \
    ca = __builtin_amdgcn_mfma_f32_16x16x32_bf16(AX[1], F[(tb)*2 + 1], ca, 0, 0, 0);
            CMM(0) c00 = ca[0]; ca = {0.f, 0.f, 0.f, 0.f};
            CMM(1) c01 = ca[0]; ca = {0.f, 0.f, 0.f, 0.f};
            CMM(2) c02 = ca[0]; ca = {0.f, 0.f, 0.f, 0.f};
            CMM(3) c03 = ca[0];
#undef CMM
        }

        // ---- c0 broadcast (value on lanes 0-15, col = lane&15)
        float c0v;
        {
            float b0 = bpermf(c00, lane & 15);
            float b1 = bpermf(c01, lane & 15);
            float b2 = bpermf(c02, lane & 15);
            float b3 = bpermf(c03, lane & 15);
            int g = lane >> 4;
            c0v = (g == 0) ? b0 : (g == 1) ? b1 : (g == 2) ? b2 : b3;
        }

        // ---- masked column sums
        float Sv = 0.f, qv = 0.f;
#define OFFT(gt, t_) (wv[t_][0] * gt[0] + wv[t_][1] * gt[1] + wv[t_][2] * gt[2] + wv[t_][3] * gt[3])
#define DIAG(d, t_)                                       \
    sp += (mb + 0 < nl) ? wv[t_][0] * d[0] : 0.f;         \
    sp += (mb + 1 < nl) ? wv[t_][1] * d[1] : 0.f;         \
    sp += (mb + 2 < nl) ? wv[t_][2] * d[2] : 0.f;         \
    sp += (mb + 3 < nl) ? wv[t_][3] * d[3] : 0.f;         \
    qp += (mb + 0 == nl) ? d[0] : 0.f;                    \
    qp += (mb + 1 == nl) ? d[1] : 0.f;                    \
    qp += (mb + 2 == nl) ? d[2] : 0.f;                    \
    qp += (mb + 3 == nl) ? d[3] : 0.f;
#define FINTN(t_)                                         \
    sp = xor16_add(sp); sp = xor32_add(sp);               \
    qp = xor16_add(qp); qp = xor32_add(qp);               \
    if ((lane >> 4) == t_) { Sv = sp; qv = qp; }
        {
            float sp = 0.f, qp = 0.f;
            DIAG(g00, 0) FINTN(0)
        }
        {
            float sp = OFFT(g01, 0), qp = 0.f;
            DIAG(g11, 1) FINTN(1)
        }
        {
            float sp = OFFT(g02, 0) + OFFT(g12, 1), qp = 0.f;
            DIAG(g22, 2) FINTN(2)
        }
        {
            float sp = OFFT(g03, 0) + OFFT(g13, 1) + OFFT(g23, 2), qp = 0.f;
            DIAG(g33, 3) FINTN(3)
        }
#undef OFFT
#undef DIAG
#undef FINTN

        float d0r = c0v + Sv;
        float qqr = qv;

        // ---- phase 3 (lane = bin)
        float tt = wl * fmaf(wl, qqr, 2.f * d0r);
        float incl = incl_scan(tt);
        float n2L = fmaxf(n2_0 + (incl - tt), 0.f);
        float n2R = fmaxf(n2_0 + incl, 0.f);
        float rrR = __builtin_amdgcn_sqrtf(n2R);
        float numerR = rrR * __expf(bsum - rrR);
        float numerL = __int_as_float(
            __builtin_amdgcn_update_dpp(0, __float_as_int(numerR), 0x138, 0xF, 0xF, true));
        numerL = (lane == 0) ? numer0 : numerL;
        float pd = fmaf(wl, qqr, d0r);
        float term = numerR * __builtin_amdgcn_rcpf(pd + EPSF)
                   - numerL * __builtin_amdgcn_rcpf(d0r + EPSF);
        float acc = reduce1(term);

        table[(size_t)pk[k] * BB + lane] = make_float4(n2L, d0r, qqr, bsum);
        accd += (double)acc;
    }
#undef ISSUE

    if (lane == 0) bacc[wid] = accd;
    __syncthreads();
    if (threadIdx.x == 0)
        atomicAdd(acc_out, bacc[0] + bacc[1] + bacc[2] + bacc[3]);
}

__global__ __launch_bounds__(256) void k_events(
    const float* __restrict__ times, const int* __restrict__ epid,
    const float* __restrict__ bounds, const float* __restrict__ innerPad,
    const float4* __restrict__ table, double* __restrict__ acc_out) {
    __shared__ float si[64];
    __shared__ float sb[BB + 1];
    __shared__ double wacc[4];
    int tid = threadIdx.x;
    if (tid < 64) si[tid] = innerPad[tid];
    if (tid <= BB) sb[tid] = bounds[tid];
    __syncthreads();
    int g = (blockIdx.x * 256 + tid) * 2;
    float2 tm2 = *(const float2*)(times + g);
    int2 pd2 = *(const int2*)(epid + g);
    float tms[2] = {tm2.x, tm2.y};
    int pids[2] = {pd2.x, pd2.y};
    int cc[2];
    float rem[2];
#pragma unroll
    for (int k = 0; k < 2; k++) {
        int c = 0;
        float tm = tms[k];
#pragma unroll
        for (int s = 32; s >= 1; s >>= 1)
            if (si[c + s - 1] <= tm) c += s;
        cc[k] = c;
        rem[k] = tm - sb[c];
    }
    float4 e0 = table[(size_t)pids[0] * BB + cc[0]];
    float4 e1 = table[(size_t)pids[1] * BB + cc[1]];
    float eacc;
    {
        float d2 = fmaxf(fmaf(rem[0], fmaf(rem[0], e0.z, 2.f * e0.y), e0.x), 0.f);
        eacc = e0.w - __builtin_amdgcn_sqrtf(d2);
        d2 = fmaxf(fmaf(rem[1], fmaf(rem[1], e1.z, 2.f * e1.y), e1.x), 0.f);
        eacc += e1.w - __builtin_amdgcn_sqrtf(d2);
    }
    float val = reduce1(eacc);
    if ((tid & 63) == 0) wacc[tid >> 6] = (double)val;
    __syncthreads();
    if (tid == 0)
        atomicAdd(acc_out, -(wacc[0] + wacc[1] + wacc[2] + wacc[3]));
}

__global__ void k_finalize(const double* __restrict__ acc, float* __restrict__ out) {
    out[0] = (float)(*acc);
}

extern "C" void kernel_launch(void* const* d_in, const int* in_sizes, int n_in,
                              void* d_out, int out_size, void* d_ws, size_t ws_size,
                              hipStream_t stream) {
    const float* x0     = (const float*)d_in[0];
    const float* v      = (const float*)d_in[1];
    const float* beta   = (const float*)d_in[2];
    const float* brw    = (const float*)d_in[3];
    const float* etimes = (const float*)d_in[4];
    const int*   pairs  = (const int*)d_in[5];
    const int*   epid   = (const int*)d_in[6];

    char* ws = (char*)d_ws;
    double* acc     = (double*)ws;
    int* cnt        = (int*)(ws + 1024);
    int* cursor     = (int*)(ws + 9216);
    int* perm       = (int*)(ws + 17408);
    float* bounds   = (float*)(ws + 82944);
    float* widths   = (float*)(ws + 83456);
    float* innerPad = (float*)(ws + 83968);
    float4* table   = (float4*)(ws + 84480);
    unsigned* vh32  = (unsigned*)(ws + 84480 + (size_t)PP * BB * 16);

    hipLaunchKernelGGL(k_bounds, dim3(9), dim3(64), 0, stream, brw, bounds, widths,
                       innerPad, cnt, acc);
    hipLaunchKernelGGL(k_convert, dim3(NN / 4), dim3(256), 0, stream, v, vh32);
    hipLaunchKernelGGL(k_hist2, dim3(PP / 256), dim3(256), 0, stream, pairs, cnt);
    hipLaunchKernelGGL(k_scan2, dim3(1), dim3(1024), 0, stream, cnt, cursor);
    hipLaunchKernelGGL(k_scatter2, dim3(PP / 256), dim3(256), 0, stream, pairs, cursor, perm);
    hipLaunchKernelGGL(k_pairs, dim3(PP / 16), dim3(256), 0, stream, x0, (const uint4*)vh32,
                       beta, pairs, perm, widths, table, acc);
    hipLaunchKernelGGL(k_events, dim3(TT / 512), dim3(256), 0, stream, etimes, epid,
                       bounds, innerPad, table, acc);
    hipLaunchKernelGGL(k_finalize, dim3(1), dim3(1), 0, stream, acc, (float*)d_out);
}

// Round 14
// 76.864 us; speedup vs baseline: 1.3443x; 1.0244x over previous
//
#include <hip/hip_runtime.h>

#define NN 2048
#define DD 64
#define BB 64
#define PP 16384
#define TT 262144
#define EPSF 1e-6f
#define SS ((size_t)NN * DD)  // floats between consecutive bins of v (bin-major)

// ---------------- ws layout (bytes) ----------------
// 0        : double acc
// 1024     : int cnt[2048]     (node-i histogram)
// 9216     : int cursor[2048]
// 17408    : int perm[PP]      (pair ids sorted by node i)
// 82944    : float bounds[65]
// 83456    : float widths[64]
// 83968    : float innerPad[64]
// 84480    : float4 table[PP*BB]  (n2_left, d0, qq, bsum) = 16.78 MB
// 16861696 : ushort vh[NN*BB*DD]  (bf16 node-major v)      = 16.78 MB

typedef unsigned uv2 __attribute__((ext_vector_type(2)));
using bf16x8 = __attribute__((ext_vector_type(8))) short;
using f32x4v = __attribute__((ext_vector_type(4))) float;

template <int CTRL, int RM = 0xF, bool BC = true>
__device__ __forceinline__ float dpp_add(float x) {
    int y = __builtin_amdgcn_update_dpp(0, __float_as_int(x), CTRL, RM, 0xF, BC);
    return x + __int_as_float(y);
}

template <int PAT>
__device__ __forceinline__ float swz_add(float x) {
    return x + __int_as_float(__builtin_amdgcn_ds_swizzle(__float_as_int(x), PAT));
}

__device__ __forceinline__ float xor16_add(float x) {
#if __has_builtin(__builtin_amdgcn_permlane16_swap)
    uv2 r = __builtin_amdgcn_permlane16_swap(__float_as_uint(x), __float_as_uint(x),
                                             false, false);
    return __uint_as_float(r.x) + __uint_as_float(r.y);
#else
    return swz_add<0x401F>(x);
#endif
}
__device__ __forceinline__ float xor32_add(float x) {
#if __has_builtin(__builtin_amdgcn_permlane32_swap)
    uv2 r = __builtin_amdgcn_permlane32_swap(__float_as_uint(x), __float_as_uint(x),
                                             false, false);
    return __uint_as_float(r.x) + __uint_as_float(r.y);
#else
    return x + __shfl_xor(x, 32, 64);
#endif
}

__device__ __forceinline__ float reduce1(float a) {
    a = dpp_add<0xB1>(a);
    a = dpp_add<0x4E>(a);
    a = dpp_add<0x141>(a);
    a = swz_add<0x201F>(a);
    a = xor16_add(a);
    a = xor32_add(a);
    return a;
}

__device__ __forceinline__ float incl_scan(float x) {
    x = dpp_add<0x111>(x);
    x = dpp_add<0x112>(x);
    x = dpp_add<0x114>(x);
    x = dpp_add<0x118>(x);
    x = dpp_add<0x142, 0xA, false>(x);
    x = dpp_add<0x143, 0xC, false>(x);
    return x;
}

__device__ __forceinline__ unsigned short f2bf(float f) {  // RNE
    unsigned u = __float_as_uint(f);
    unsigned r = (u + 0x7FFFu + ((u >> 16) & 1u)) >> 16;
    return (unsigned short)r;
}
__device__ __forceinline__ float bf_lo(unsigned u) { return __uint_as_float(u << 16); }
__device__ __forceinline__ float bf_hi(unsigned u) { return __uint_as_float(u & 0xFFFF0000u); }

__device__ __forceinline__ unsigned cvt_pk_bf(float lo, float hi) {
    unsigned r;
    asm("v_cvt_pk_bf16_f32 %0, %1, %2" : "=v"(r) : "v"(lo), "v"(hi));
    return r;
}
__device__ __forceinline__ float bpermf(float v, int srclane) {
    return __int_as_float(__builtin_amdgcn_ds_bpermute(srclane << 2, __float_as_int(v)));
}

__global__ void k_bounds(const float* __restrict__ brw, float* __restrict__ bounds,
                         float* __restrict__ widths, float* __restrict__ innerPad,
                         int* __restrict__ cnt, double* __restrict__ acc) {
    if (blockIdx.x != 0) {
        int t = (blockIdx.x - 1) * 64 + threadIdx.x;
#pragma unroll
        for (int k = 0; k < 4; k++) cnt[t * 4 + k] = 0;
        if (blockIdx.x == 1 && threadIdx.x == 0) acc[0] = 0.0;
        return;
    }
    int lane = threadIdx.x;
    float w = brw[lane];
    float m = w;
#pragma unroll
    for (int s = 32; s >= 1; s >>= 1) m = fmaxf(m, __shfl_xor(m, s, 64));
    float e = expf(w - m);
    float tot = e;
#pragma unroll
    for (int s = 32; s >= 1; s >>= 1) tot += __shfl_xor(tot, s, 64);
    float sm = e / tot;
    float c = sm;
#pragma unroll
    for (int off = 1; off < 64; off <<= 1) {
        float t = __shfl_up(c, off, 64);
        if (lane >= off) c += t;
    }
    float cexcl = __shfl_up(c, 1, 64);
    if (lane == 0) cexcl = 0.f;
    if (lane == 0) bounds[0] = 0.f;
    bounds[lane + 1] = c;
    widths[lane] = c - cexcl;
    innerPad[lane] = (lane == 63) ? 3.4e38f : c;
}

// fused: blocks [0,512) convert v->bf16 node-major; blocks [512,576) histogram pairs
__global__ __launch_bounds__(256) void k_convert_hist(const float* __restrict__ v,
                                                      unsigned* __restrict__ vh32,
                                                      const int* __restrict__ pairs,
                                                      int* __restrict__ cnt) {
    if (blockIdx.x >= NN / 4) {
        int t = (blockIdx.x - NN / 4) * 256 + threadIdx.x;  // t < PP
        atomicAdd(&cnt[pairs[t]], 1);
        return;
    }
    int wid = threadIdx.x >> 6, lane = threadIdx.x & 63;
    int n = blockIdx.x * 4 + wid;
    int sub = lane >> 5;
    int dp = (lane & 31) * 2;
    unsigned* __restrict__ dst = vh32 + ((size_t)n * BB * DD) / 2;
#pragma unroll
    for (int c = 0; c < 32; c++) {
        int b = c * 2 + sub;
        float2 f = *(const float2*)(v + (size_t)b * SS + (size_t)n * DD + dp);
        unsigned pk = (unsigned)f2bf(f.x) | ((unsigned)f2bf(f.y) << 16);
        dst[(b * DD + dp) / 2] = pk;
    }
}

__global__ __launch_bounds__(1024) void k_scan2(const int* __restrict__ cnt,
                                                int* __restrict__ cursor) {
    __shared__ int waveTot[16];
    __shared__ int waveOff[16];
    int tid = threadIdx.x;
    int a = cnt[tid * 2], b = cnt[tid * 2 + 1];
    int s = a + b;
    int lane = tid & 63, wid = tid >> 6;
    int incl = s;
#pragma unroll
    for (int off = 1; off < 64; off <<= 1) {
        int t2 = __shfl_up(incl, off, 64);
        if (lane >= off) incl += t2;
    }
    if (lane == 63) waveTot[wid] = incl;
    __syncthreads();
    if (tid == 0) {
        int r = 0;
        for (int w = 0; w < 16; w++) { waveOff[w] = r; r += waveTot[w]; }
    }
    __syncthreads();
    int run = waveOff[wid] + (incl - s);
    cursor[tid * 2] = run;
    cursor[tid * 2 + 1] = run + a;
}

__global__ void k_scatter2(const int* __restrict__ pairs, int* __restrict__ cursor,
                           int* __restrict__ perm) {
    int t = blockIdx.x * 256 + threadIdx.x;
    int pos = atomicAdd(&cursor[pairs[t]], 1);
    perm[pos] = t;
}

// 8 pairs per wave, 2-deep double-buffered staging: bursts for pairs k+1 and
// k+2 are in flight while pair k computes (~2 compute phases of latency cover).
__global__ __launch_bounds__(256, 2) void k_pairs(
    const float* __restrict__ x0, const uint4* __restrict__ vh4,
    const float* __restrict__ beta, const int* __restrict__ pairs,
    const int* __restrict__ perm, const float* __restrict__ widths,
    float4* __restrict__ table, double* __restrict__ acc_out) {
    __shared__ double bacc[4];
    const int wid = threadIdx.x >> 6;
    const int lane = threadIdx.x & 63;
    const int bid = blockIdx.x;
    const int vb = ((bid & 7) << 6) | (bid >> 3);  // XCD swizzle over 512 blocks
    const int pbase = (vb * 4 + wid) * 8;

    int pk[8], ik[8], jk[8];
    float bs[8];
#pragma unroll
    for (int k = 0; k < 8; k++) pk[k] = perm[pbase + k];
#pragma unroll
    for (int k = 0; k < 8; k++) {
        ik[k] = pairs[pk[k]];
        jk[k] = pairs[PP + pk[k]];
    }
#pragma unroll
    for (int k = 0; k < 8; k++) bs[k] = beta[ik[k]] + beta[jk[k]];

    float wv[4][4];
#pragma unroll
    for (int tm = 0; tm < 4; tm++)
#pragma unroll
        for (int r = 0; r < 4; r++)
            wv[tm][r] = widths[16 * tm + (lane >> 4) * 4 + r];
    const float wl = widths[lane];
    const int laneterm = (lane & 15) * 8 + (lane >> 4);
    const int nl = lane & 15;
    const int mb = (lane >> 4) * 4;

    // two staging buffers (compile-time selected — no runtime indexing)
    uint4 ra0[8], rb0[8], ra1[8], rb1[8];
    float xi0, xj0, xi1, xj1;

#define ISSUE(RA, RB, XI, XJ, k_)                                            \
    {                                                                        \
        const uint4* Vi = vh4 + (size_t)ik[k_] * 512 + laneterm;             \
        const uint4* Vj = vh4 + (size_t)jk[k_] * 512 + laneterm;             \
        _Pragma("unroll") for (int t = 0; t < 4; t++) {                      \
            RA[t * 2 + 0] = Vi[t * 128];                                     \
            RA[t * 2 + 1] = Vi[t * 128 + 4];                                 \
            RB[t * 2 + 0] = Vj[t * 128];                                     \
            RB[t * 2 + 1] = Vj[t * 128 + 4];                                 \
        }                                                                    \
        XI = x0[ik[k_] * DD + lane];                                         \
        XJ = x0[jk[k_] * DD + lane];                                         \
    }

    double accd = 0.0;

#define STEP(RA, RB, XI, XJ, k_, NEXTISSUE)                                                    \
    {                                                                                          \
        const float bsum = bs[k_];                                                             \
        float dx0 = XI - XJ;                                                                   \
        float n2_0 = reduce1(dx0 * dx0);                                                       \
        float rr0 = __builtin_amdgcn_sqrtf(n2_0);                                              \
        float numer0 = rr0 * __expf(bsum - rr0);                                               \
        bf16x8 F[8];                                                                           \
        _Pragma("unroll") for (int f = 0; f < 8; f++) {                                        \
            uint4 q;                                                                           \
            q.x = cvt_pk_bf(bf_lo(RA[f].x) - bf_lo(RB[f].x), bf_hi(RA[f].x) - bf_hi(RB[f].x)); \
            q.y = cvt_pk_bf(bf_lo(RA[f].y) - bf_lo(RB[f].y), bf_hi(RA[f].y) - bf_hi(RB[f].y)); \
            q.z = cvt_pk_bf(bf_lo(RA[f].z) - bf_lo(RB[f].z), bf_hi(RA[f].z) - bf_hi(RB[f].z)); \
            q.w = cvt_pk_bf(bf_lo(RA[f].w) - bf_lo(RB[f].w), bf_hi(RA[f].w) - bf_hi(RB[f].w)); \
            union { uint4 u; bf16x8 s; } cv;                                                   \
            cv.u = q;                                                                          \
            F[f] = cv.s;                                                                       \
        }                                                                                      \
        NEXTISSUE                                                                              \
        bf16x8 AX[2];                                                                          \
        _Pragma("unroll") for (int kb = 0; kb < 2; kb++) {                                     \
            unsigned u[4];                                                                     \
            _Pragma("unroll") for (int c2 = 0; c2 < 4; c2++) {                                 \
                int k0 = kb * 32 + ((lane >> 4) << 3) + c2 * 2;                                \
                u[c2] = cvt_pk_bf(bpermf(dx0, k0), bpermf(dx0, k0 + 1));                       \
            }                                                                                  \
            uint4 q;                                                                           \
            bool z = (lane & 15) != 0;                                                         \
            q.x = z ? 0u : u[0]; q.y = z ? 0u : u[1];                                          \
            q.z = z ? 0u : u[2]; q.w = z ? 0u : u[3];                                          \
            union { uint4 uu; bf16x8 s; } cv;                                                  \
            cv.uu = q;                                                                         \
            AX[kb] = cv.s;                                                                     \
        }                                                                                      \
        f32x4v g00 = {0.f, 0.f, 0.f, 0.f}, g01 = g00, g02 = g00, g03 = g00;                    \
        f32x4v g11 = g00, g12 = g00, g13 = g00, g22 = g00, g23 = g00, g33 = g00;               \
        GMM(g00, 0, 0) GMM(g01, 0, 1) GMM(g02, 0, 2) GMM(g03, 0, 3)                            \
        GMM(g11, 1, 1) GMM(g12, 1, 2) GMM(g13, 1, 3)                                           \
        GMM(g22, 2, 2) GMM(g23, 2, 3) GMM(g33, 3, 3)                                           \
        float c00, c01, c02, c03;                                                              \
        {                                                                                      \
            f32x4v ca = {0.f, 0.f, 0.f, 0.f};                                                  \
            CMM(0) c00 = ca[0]; ca = {0.f, 0.f, 0.f, 0.f};                                     \
            CMM(1) c01 = ca[0]; ca = {0.f, 0.f, 0.f, 0.f};                                     \
            CMM(2) c02 = ca[0]; ca = {0.f, 0.f, 0.f, 0.f};                                     \
            CMM(3) c03 = ca[0];                                                                \
        }                                                                                      \
        float c0v;                                                                             \
        {                                                                                      \
            float b0 = bpermf(c00, lane & 15);                                                 \
            float b1 = bpermf(c01, lane & 15);                                                 \
            float b2 = bpermf(c02, lane & 15);                                                 \
            float b3 = bpermf(c03, lane & 15);                                                 \
            int g = lane >> 4;                                                                 \
            c0v = (g == 0) ? b0 : (g == 1) ? b1 : (g == 2) ? b2 : b3;                          \
        }                                                                                      \
        float Sv = 0.f, qv = 0.f;                                                              \
        { float sp = 0.f, qp = 0.f;                                 DIAG(g00, 0) FINTN(0) }    \
        { float sp = OFFT(g01, 0), qp = 0.f;                        DIAG(g11, 1) FINTN(1) }    \
        { float sp = OFFT(g02, 0) + OFFT(g12, 1), qp = 0.f;         DIAG(g22, 2) FINTN(2) }    \
        { float sp = OFFT(g03, 0) + OFFT(g13, 1) + OFFT(g23, 2), qp = 0.f;                     \
                                                                    DIAG(g33, 3) FINTN(3) }    \
        float d0r = c0v + Sv;                                                                  \
        float qqr = qv;                                                                        \
        float tt = wl * fmaf(wl, qqr, 2.f * d0r);                                              \
        float incl = incl_scan(tt);                                                            \
        float n2L = fmaxf(n2_0 + (incl - tt), 0.f);                                            \
        float n2R = fmaxf(n2_0 + incl, 0.f);                                                   \
        float rrR = __builtin_amdgcn_sqrtf(n2R);                                               \
        float numerR = rrR * __expf(bsum - rrR);                                               \
        float numerL = __int_as_float(                                                         \
            __builtin_amdgcn_update_dpp(0, __float_as_int(numerR), 0x138, 0xF, 0xF, true));    \
        numerL = (lane == 0) ? numer0 : numerL;                                                \
        float pd = fmaf(wl, qqr, d0r);                                                         \
        float term = numerR * __builtin_amdgcn_rcpf(pd + EPSF)                                 \
                   - numerL * __builtin_amdgcn_rcpf(d0r + EPSF);                               \
        float acc = reduce1(term);                                                             \
        table[(size_t)pk[k_] * BB + lane] = make_float4(n2L, d0r, qqr, bsum);                  \
        accd += (double)acc;                                                                   \
    }

#define GMM(acc, ta, tb)                                                                       \
    acc = __builtin_amdgcn_mfma_f32_16x16x32_bf16(F[(ta)*2 + 0], F[(tb)*2 + 0], acc, 0, 0, 0); \
    acc = __builtin_amdgcn_mfma_f32_16x16x32_bf16(F[(ta)*2 + 1], F[(tb)*2 + 1], acc, 0, 0, 0);
#define CMM(tb)                                                                       \
    ca = __builtin_amdgcn_mfma_f32_16x16x32_bf16(AX[0], F[(tb)*2 + 0], ca, 0, 0, 0); \
    ca = __builtin_amdgcn_mfma_f32_16x16x32_bf16(AX[1], F[(tb)*2 + 1], ca, 0, 0, 0);
#define OFFT(gt, t_) (wv[t_][0] * gt[0] + wv[t_][1] * gt[1] + wv[t_][2] * gt[2] + wv[t_][3] * gt[3])
#define DIAG(d, t_)                                       \
    sp += (mb + 0 < nl) ? wv[t_][0] * d[0] : 0.f;         \
    sp += (mb + 1 < nl) ? wv[t_][1] * d[1] : 0.f;         \
    sp += (mb + 2 < nl) ? wv[t_][2] * d[2] : 0.f;         \
    sp += (mb + 3 < nl) ? wv[t_][3] * d[3] : 0.f;         \
    qp += (mb + 0 == nl) ? d[0] : 0.f;                    \
    qp += (mb + 1 == nl) ? d[1] : 0.f;                    \
    qp += (mb + 2 == nl) ? d[2] : 0.f;                    \
    qp += (mb + 3 == nl) ? d[3] : 0.f;
#define FINTN(t_)                                         \
    sp = xor16_add(sp); sp = xor32_add(sp);               \
    qp = xor16_add(qp); qp = xor32_add(qp);               \
    if ((lane >> 4) == t_) { Sv = sp; qv = qp; }

    ISSUE(ra0, rb0, xi0, xj0, 0)
    ISSUE(ra1, rb1, xi1, xj1, 1)

    STEP(ra0, rb0, xi0, xj0, 0, ISSUE(ra0, rb0, xi0, xj0, 2))
    STEP(ra1, rb1, xi1, xj1, 1, ISSUE(ra1, rb1, xi1, xj1, 3))
    STEP(ra0, rb0, xi0, xj0, 2, ISSUE(ra0, rb0, xi0, xj0, 4))
    STEP(ra1, rb1, xi1, xj1, 3, ISSUE(ra1, rb1, xi1, xj1, 5))
    STEP(ra0, rb0, xi0, xj0, 4, ISSUE(ra0, rb0, xi0, xj0, 6))
    STEP(ra1, rb1, xi1, xj1, 5, ISSUE(ra1, rb1, xi1, xj1, 7))
    STEP(ra0, rb0, xi0, xj0, 6, )
    STEP(ra1, rb1, xi1, xj1, 7, )

#undef ISSUE
#undef STEP
#undef GMM
#undef CMM
#undef OFFT
#undef DIAG
#undef FINTN

    if (lane == 0) bacc[wid] = accd;
    __syncthreads();
    if (threadIdx.x == 0)
        atomicAdd(acc_out, bacc[0] + bacc[1] + bacc[2] + bacc[3]);
}

__global__ __launch_bounds__(256) void k_events(
    const float* __restrict__ times, const int* __restrict__ epid,
    const float* __restrict__ bounds, const float* __restrict__ innerPad,
    const float4* __restrict__ table, double* __restrict__ acc_out) {
    __shared__ float si[64];
    __shared__ float sb[BB + 1];
    __shared__ double wacc[4];
    int tid = threadIdx.x;
    if (tid < 64) si[tid] = innerPad[tid];
    if (tid <= BB) sb[tid] = bounds[tid];
    __syncthreads();
    int g = (blockIdx.x * 256 + tid) * 2;
    float2 tm2 = *(const float2*)(times + g);
    int2 pd2 = *(const int2*)(epid + g);
    float tms[2] = {tm2.x, tm2.y};
    int pids[2] = {pd2.x, pd2.y};
    int cc[2];
    float rem[2];
#pragma unroll
    for (int k = 0; k < 2; k++) {
        int c = 0;
        float tm = tms[k];
#pragma unroll
        for (int s = 32; s >= 1; s >>= 1)
            if (si[c + s - 1] <= tm) c += s;
        cc[k] = c;
        rem[k] = tm - sb[c];
    }
    float4 e0 = table[(size_t)pids[0] * BB + cc[0]];
    float4 e1 = table[(size_t)pids[1] * BB + cc[1]];
    float eacc;
    {
        float d2 = fmaxf(fmaf(rem[0], fmaf(rem[0], e0.z, 2.f * e0.y), e0.x), 0.f);
        eacc = e0.w - __builtin_amdgcn_sqrtf(d2);
        d2 = fmaxf(fmaf(rem[1], fmaf(rem[1], e1.z, 2.f * e1.y), e1.x), 0.f);
        eacc += e1.w - __builtin_amdgcn_sqrtf(d2);
    }
    float val = reduce1(eacc);
    if ((tid & 63) == 0) wacc[tid >> 6] = (double)val;
    __syncthreads();
    if (tid == 0)
        atomicAdd(acc_out, -(wacc[0] + wacc[1] + wacc[2] + wacc[3]));
}

__global__ void k_finalize(const double* __restrict__ acc, float* __restrict__ out) {
    out[0] = (float)(*acc);
}

extern "C" void kernel_launch(void* const* d_in, const int* in_sizes, int n_in,
                              void* d_out, int out_size, void* d_ws, size_t ws_size,
                              hipStream_t stream) {
    const float* x0     = (const float*)d_in[0];
    const float* v      = (const float*)d_in[1];
    const float* beta   = (const float*)d_in[2];
    const float* brw    = (const float*)d_in[3];
    const float* etimes = (const float*)d_in[4];
    const int*   pairs  = (const int*)d_in[5];
    const int*   epid   = (const int*)d_in[6];

    char* ws = (char*)d_ws;
    double* acc     = (double*)ws;
    int* cnt        = (int*)(ws + 1024);
    int* cursor     = (int*)(ws + 9216);
    int* perm       = (int*)(ws + 17408);
    float* bounds   = (float*)(ws + 82944);
    float* widths   = (float*)(ws + 83456);
    float* innerPad = (float*)(ws + 83968);
    float4* table   = (float4*)(ws + 84480);
    unsigned* vh32  = (unsigned*)(ws + 84480 + (size_t)PP * BB * 16);

    hipLaunchKernelGGL(k_bounds, dim3(9), dim3(64), 0, stream, brw, bounds, widths,
                       innerPad, cnt, acc);
    hipLaunchKernelGGL(k_convert_hist, dim3(NN / 4 + PP / 256), dim3(256), 0, stream,
                       v, vh32, pairs, cnt);
    hipLaunchKernelGGL(k_scan2, dim3(1), dim3(1024), 0, stream, cnt, cursor);
    hipLaunchKernelGGL(k_scatter2, dim3(PP / 256), dim3(256), 0, stream, pairs, cursor, perm);
    hipLaunchKernelGGL(k_pairs, dim3(PP / 32), dim3(256), 0, stream, x0, (const uint4*)vh32,
                       beta, pairs, perm, widths, table, acc);
    hipLaunchKernelGGL(k_events, dim3(TT / 512), dim3(256), 0, stream, etimes, epid,
                       bounds, innerPad, table, acc);
    hipLaunchKernelGGL(k_finalize, dim3(1), dim3(1), 0, stream, acc, (float*)d_out);
}